// Round 3
// baseline (239.019 us; speedup 1.0000x reference)
//
#include <hip/hip_runtime.h>

typedef float vf2  __attribute__((ext_vector_type(2)));
typedef float v128f __attribute__((ext_vector_type(128)));

__device__ __forceinline__ vf2 cmulv(vf2 a, vf2 b){
  vf2 br; br.x = -b.y; br.y = b.x;
  return a.x*b + a.y*br;
}

#define ROWS 66   // transpose-buffer row stride in float2 (64 + 2 pad -> bank stagger)
#define FENCE() asm volatile("" ::: "memory")

// 6 RY gates on the reg-domain bits of the big-vector state (sl, par may be runtime)
#define GATES6(sl, par) do{ \
  _Pragma("unroll") \
  for (int lb = 0; lb < 6; lb++){ \
    const int wire_ = (par) ? (5 - lb) : (11 - lb); \
    vf2 cs_ = scsl[(sl)*12 + wire_]; \
    const float c_ = cs_.x, sn_ = cs_.y; \
    _Pragma("unroll") \
    for (int w0 = 0; w0 < 64; w0++){ \
      if (w0 & (1 << lb)) continue; \
      const int w1 = w0 | (1 << lb); \
      vf2 a_, b_, r0_, r1_; \
      a_.x = st[2*w0]; a_.y = st[2*w0+1]; \
      b_.x = st[2*w1]; b_.y = st[2*w1+1]; \
      r0_ = c_*a_ - sn_*b_; \
      r1_ = sn_*a_ + c_*b_; \
      st[2*w0] = r0_.x; st[2*w0+1] = r0_.y; \
      st[2*w1] = r1_.x; st[2*w1+1] = r1_.y; \
    } \
  } \
}while(0)

// Two-phase 64x64 lane<->reg transpose through a 32-row LDS buffer.  Phase A moves
// the cross blocks: lanes<32 export regs 32..63 / import new regs 32..63 (which they
// just exported -> no hazard, no stash); lanes>=32 symmetric.  Phase B moves the
// diagonal blocks.  All st[] indices are compile-time; only LDS addresses depend on
// the lane.  Per-wave in-order LDS pipe gives cross-lane RAW/WAR ordering within the
// wave (each wave owns a private xbuf region); FENCE() stops the compiler from
// reordering the (provably column-disjoint) accesses across phases.
#define TRANSPOSE() do{ \
  if (u < 32){ \
    _Pragma("unroll") \
    for (int w = 32; w < 64; w++){ vf2 t_; t_.x = st[2*w]; t_.y = st[2*w+1]; \
      xbuf[(w-32) * ROWS + u] = t_; } \
  } else { \
    _Pragma("unroll") \
    for (int w = 0; w < 32; w++){ vf2 t_; t_.x = st[2*w]; t_.y = st[2*w+1]; \
      xbuf[w * ROWS + u] = t_; } \
  } \
  FENCE(); \
  if (u < 32){ \
    _Pragma("unroll") \
    for (int t = 0; t < 16; t++){ \
      float4 f_ = ((const float4*)&xbuf[u * ROWS + 32])[t]; \
      st[64+4*t] = f_.x; st[64+4*t+1] = f_.y; st[64+4*t+2] = f_.z; st[64+4*t+3] = f_.w; } \
  } else { \
    _Pragma("unroll") \
    for (int t = 0; t < 16; t++){ \
      float4 f_ = ((const float4*)&xbuf[(u-32) * ROWS])[t]; \
      st[4*t] = f_.x; st[4*t+1] = f_.y; st[4*t+2] = f_.z; st[4*t+3] = f_.w; } \
  } \
  FENCE(); \
  if (u < 32){ \
    _Pragma("unroll") \
    for (int w = 0; w < 32; w++){ vf2 t_; t_.x = st[2*w]; t_.y = st[2*w+1]; \
      xbuf[w * ROWS + u] = t_; } \
  } else { \
    _Pragma("unroll") \
    for (int w = 32; w < 64; w++){ vf2 t_; t_.x = st[2*w]; t_.y = st[2*w+1]; \
      xbuf[(w-32) * ROWS + u] = t_; } \
  } \
  FENCE(); \
  if (u < 32){ \
    _Pragma("unroll") \
    for (int t = 0; t < 16; t++){ \
      float4 f_ = ((const float4*)&xbuf[u * ROWS])[t]; \
      st[4*t] = f_.x; st[4*t+1] = f_.y; st[4*t+2] = f_.z; st[4*t+3] = f_.w; } \
  } else { \
    _Pragma("unroll") \
    for (int t = 0; t < 16; t++){ \
      float4 f_ = ((const float4*)&xbuf[(u-32) * ROWS + 32])[t]; \
      st[64+4*t] = f_.x; st[64+4*t+1] = f_.y; st[64+4*t+2] = f_.z; st[64+4*t+3] = f_.w; } \
  } \
  FENCE(); \
}while(0)

// merged diagonal (runtime par): reg part from tabs1, lane part from ltab1,
// cross CZ terms inline
#define DIAG(par) do{ \
  vf2 lp_ = ltab1[u]; \
  vf2 lpn_ = -lp_; \
  const int u0_ = u & 1, u1_ = (u >> 1) & 1, u4_ = (u >> 4) & 1, u5_ = (u >> 5) & 1; \
  _Pragma("unroll") \
  for (int w = 0; w < 64; w++){ \
    vf2 dph_ = tabs1[w]; \
    int sx_; \
    if (par) sx_ = ((w & 1) * u5_) ^ (((w >> 5) & 1) * u0_); \
    else     sx_ = (((w >> 5) & 1) * u1_) ^ (((w >> 4) & 1) * u0_) \
                 ^ (((w >> 1) & 1) * u5_) ^ ((w & 1) * u4_); \
    vf2 a_; a_.x = st[2*w]; a_.y = st[2*w+1]; \
    vf2 t_ = cmulv(a_, dph_); \
    vf2 r_ = cmulv(t_, sx_ ? lpn_ : lp_); \
    st[2*w] = r_.x; st[2*w+1] = r_.y; \
  } \
}while(0)

__global__ __attribute__((amdgpu_flat_work_group_size(128,128)))
__attribute__((amdgpu_waves_per_eu(1,8)))
void qiddm_wave(const float* __restrict__ gx,
                const float* __restrict__ gcw,
                const float* __restrict__ gcb,
                const float* __restrict__ gw1,
                const float* __restrict__ glw,
                const float* __restrict__ glb,
                float* __restrict__ gout)
{
  // TWO waves per workgroup, each wave = one sample, fully independent (no barriers).
  // Round-2 finding: single-wave WGs cap at ~4 WGs/CU regardless of LDS (occupancy
  // stuck at 11%, VALUBusy 51%).  Packing 2 waves/WG turns the same ~4 WG slots into
  // 8 waves/CU = 2 waves/SIMD so co-resident waves hide each other's LDS/VALU latency.
  // L0 layout: lane u = idx bits 11..6 (wires 0..5), reg w = idx bits 5..0 (wires 6..11)
  // L1 layout: lane u = idx bits 5..0,  reg w = idx bits 11..6
  // LDS: 2 x (16896 + 512 + 512 + 576) = 36992 B -> 4 WGs/CU (163840/36992 = 4.4)
  __shared__ vf2 xbuf_s[2][32 * ROWS];  // per-wave two-phase transpose buffer
  __shared__ vf2 tabs1_s[2][64];        // per-wave reg-domain diagonal table (JIT-built)
  __shared__ vf2 ltab1_s[2][64];        // per-wave lane-domain diagonal factors
  __shared__ vf2 scsl_s[2][72];         // per-wave (cos, sin) of theta/2 per (sublayer, wire)

  const int u  = threadIdx.x & 63;      // lane 0..63 within the wave
  const int wv = threadIdx.x >> 6;      // wave id 0..1
  const int sid = blockIdx.x * 2 + wv;  // sample id

  vf2* const xbuf  = xbuf_s[wv];
  vf2* const tabs1 = tabs1_s[wv];
  vf2* const ltab1 = ltab1_s[wv];
  vf2* const scsl  = scsl_s[wv];

  float xr[12];                         // circuit inputs / expvals (constant-indexed only)

  // ---------- conv 3x3 s2 p1 + bias + GAP ----------
  {
    float* img = (float*)xbuf;          // 4096 B < 16896 B, wave-private
#pragma unroll
    for (int i = 0; i < 4; i++){
      float4 q4 = ((const float4*)gx)[(size_t)sid * 256 + i * 64 + u];
      ((float4*)img)[i * 64 + u] = q4;
    }
    float p[4][9];
#pragma unroll
    for (int i = 0; i < 4; i++){
      int pos = u + 64 * i, oi = pos >> 4, oj = pos & 15;
#pragma unroll
      for (int ki = 0; ki < 3; ki++)
#pragma unroll
        for (int kj = 0; kj < 3; kj++){
          int ri = 2*oi - 1 + ki, cj = 2*oj - 1 + kj;
          p[i][ki*3+kj] = (ri >= 0 && ri < 32 && cj >= 0 && cj < 32) ? img[ri*32+cj] : 0.0f;
        }
    }
#pragma unroll
    for (int q = 0; q < 12; q++){
      float a = 0.0f;
#pragma unroll
      for (int e = 0; e < 9; e++){
        float wv_ = gcw[q*9+e];                 // uniform -> scalarized
#pragma unroll
        for (int i = 0; i < 4; i++) a += p[i][e] * wv_;
      }
#pragma unroll
      for (int off = 32; off; off >>= 1) a += __shfl_xor(a, off);
      xr[q] = gcb[q] + a * (1.0f/256.0f);
    }
  }

#pragma unroll 1
  for (int n = 0; n < 2; n++){
    const float* W = gw1 + n * 216;

    // ---- RY cos/sin table (72 gates) ----
#pragma unroll
    for (int rep = 0; rep < 2; rep++){
      int e = u + rep * 64;
      if (e < 72){
        float sv, cv; __sincosf(0.5f * W[e*3+1], &sv, &cv);
        vf2 cs; cs.x = cv; cs.y = sv; scsl[e] = cs;
      }
    }

    // ---- circuit: |0>, 12 half-sublayer steps, measure ----
    v128f st;
#pragma unroll
    for (int w = 0; w < 64; w++){ st[2*w] = 0.f; st[2*w+1] = 0.f; }
    if (u == 0) st[0] = 1.f;                    // idx 0 = (lane 0, reg 0)

    GATES6(0, 0);                               // k=0: s0 on wires 6..11 (L0)
#pragma unroll 1
    for (int k = 1; k < 12; k++){
      const int sl  = k >> 1;
      const int par = ((k + 1) >> 1) & 1;
      if (k & 1){
        TRANSPOSE();                            // flip lane/reg domains
      } else {
        // ---- JIT build of diagonal d = sl (runtime, sequential 1..5) ----
        // par is wave-uniform -> uniform branch; xr[] indices compile-time in each arm
        const int dd = (sl >> 1) * 2;
        float ph_r = 0.f, ph_l = 0.f;
        if (par){                               // odd d: weights only
#pragma unroll
          for (int lb = 0; lb < 6; lb++){
            const float bit = (float)((u >> lb) & 1) - 0.5f;
            ph_r += (W[((dd+1)*12+(5-lb))*3+0] + W[(dd*12+(5-lb))*3+2]) * bit;
            ph_l += (W[((dd+1)*12+(11-lb))*3+0] + W[(dd*12+(11-lb))*3+2]) * bit;
          }
        } else {                                // even d: includes encoder angles xr
#pragma unroll
          for (int lb = 0; lb < 6; lb++){
            const float bit = (float)((u >> lb) & 1) - 0.5f;
            ph_r += (W[(dd*12+(11-lb))*3+0] + xr[11-lb] + W[((dd-1)*12+(11-lb))*3+2]) * bit;
            ph_l += (W[(dd*12+(5-lb))*3+0] + xr[5-lb] + W[((dd-1)*12+(5-lb))*3+2]) * bit;
          }
        }
        {
          const int r_ = par ? 1 : 2;
          int idx = par ? (u << 6) : u;         // reg-domain basis index
          int y = ((idx << r_) | (idx >> (12 - r_))) & 0xFFF;
          int s = __popc(idx & y) & 1;          // within-reg CZ parity
          float sv, cv; __sincosf(ph_r, &sv, &cv);
          vf2 e_; e_.x = cv; e_.y = sv; if (s) e_ = -e_;
          tabs1[u] = e_;
          idx = par ? u : (u << 6);             // lane-domain basis index
          y = ((idx << r_) | (idx >> (12 - r_))) & 0xFFF;
          s = __popc(idx & y) & 1;              // within-lane CZ parity
          __sincosf(ph_l, &sv, &cv);
          vf2 e2_; e2_.x = cv; e2_.y = sv; if (s) e2_ = -e2_;
          ltab1[u] = e2_;
        }
        FENCE();                                // build writes before DIAG broadcast reads
        DIAG(par);                              // D_sl before the sublayer's 2nd half
      }
      GATES6(sl, par);
    }

    // ---- measurement in L0 (final omega-diagonal is a pure phase: dropped) ----
    {
      float P = 0.f, mm[6] = {0.f,0.f,0.f,0.f,0.f,0.f};  // wires 6..11 (reg bits 5..0)
#pragma unroll
      for (int w = 0; w < 64; w++){
        float re = st[2*w], im = st[2*w+1];
        float pr = re*re + im*im;
        P += pr;
#pragma unroll
        for (int i = 0; i < 6; i++)
          mm[i] += ((w >> (5 - i)) & 1) ? -pr : pr;
      }
#pragma unroll
      for (int q = 0; q < 12; q++){
        float val = (q < 6) ? (((u >> (5 - q)) & 1) ? -P : P)   // wires 0..5 (lane bits)
                            : mm[q - 6];
#pragma unroll
        for (int off = 32; off; off >>= 1) val += __shfl_xor(val, off);
        xr[q] = val;                            // uniform across lanes after butterfly
      }
    }
  }

  // ---------- final linear ----------
  {
#pragma unroll
    for (int i = 0; i < 16; i++){
      int o = i * 64 + u;
      const float4* wr = (const float4*)(glw + o * 12);   // 48B rows, 16B aligned
      float4 w0 = wr[0], w1 = wr[1], w2 = wr[2];
      float a = glb[o];
      a += xr[0]*w0.x + xr[1]*w0.y + xr[2]*w0.z + xr[3]*w0.w;
      a += xr[4]*w1.x + xr[5]*w1.y + xr[6]*w1.z + xr[7]*w1.w;
      a += xr[8]*w2.x + xr[9]*w2.y + xr[10]*w2.z + xr[11]*w2.w;
      gout[(size_t)sid * 1024 + o] = a;
    }
  }
}

extern "C" void kernel_launch(void* const* d_in, const int* in_sizes, int n_in,
                              void* d_out, int out_size, void* d_ws, size_t ws_size,
                              hipStream_t stream)
{
  (void)n_in; (void)d_ws; (void)ws_size; (void)out_size;
  const float* x  = (const float*)d_in[0];
  const float* cw = (const float*)d_in[1];
  const float* cb = (const float*)d_in[2];
  const float* w1 = (const float*)d_in[3];
  const float* lw = (const float*)d_in[4];
  const float* lb = (const float*)d_in[5];
  float* out = (float*)d_out;
  const int nb = in_sizes[0] / 1024;   // 2048 samples, 2 per workgroup
  hipLaunchKernelGGL(qiddm_wave, dim3(nb / 2), dim3(128), 0, stream,
                     x, cw, cb, w1, lw, lb, out);
}

// Round 4
// 212.077 us; speedup vs baseline: 1.1270x; 1.1270x over previous
//
#include <hip/hip_runtime.h>

typedef float vf2  __attribute__((ext_vector_type(2)));
typedef float v128f __attribute__((ext_vector_type(128)));

__device__ __forceinline__ vf2 cmulv(vf2 a, vf2 b){
  vf2 br; br.x = -b.y; br.y = b.x;
  return a.x*b + a.y*br;
}

#define ROWS 66   // transpose-buffer row stride in float2 (64 + 2 pad -> bank stagger)
#define FENCE() asm volatile("" ::: "memory")

// merged-diagonal angle for wire j of diagonal d (wave-uniform); d, j compile-time
#define ALPHA(d, j) (((d) & 1) \
  ? (W[((((d)>>1)*2+1)*12+(j))*3+0] + W[((((d)>>1)*2+0)*12+(j))*3+2]) \
  : (W[((((d)>>1)*2+0)*12+(j))*3+0] + xr[(j)] + W[(((((d)>>1)-1)*2+1)*12+(j))*3+2]))

// 6 RY gates on the reg-domain bits, PACKED: each butterfly is 2x(v_pk_mul+v_pk_fma)
// = 4 VALU instrs instead of 8 scalar (the compiler does not form v_pk_* from vf2
// expressions on its own -- round-0..3 counters show scalar-count VALU issue).
// Splat constants hoisted per lb stage (amortized over 32 butterflies).
#define GATES6(sl, par) do{ \
  _Pragma("unroll") \
  for (int lb = 0; lb < 6; lb++){ \
    const int wire_ = (par) ? (5 - lb) : (11 - lb); \
    vf2 cs_ = scsl[(sl)*12 + wire_]; \
    vf2 cc_; cc_.x = cs_.x; cc_.y = cs_.x; \
    vf2 ss_; ss_.x = cs_.y; ss_.y = cs_.y; \
    vf2 ns_ = -ss_; \
    _Pragma("unroll") \
    for (int w0 = 0; w0 < 64; w0++){ \
      if (w0 & (1 << lb)) continue; \
      const int w1 = w0 | (1 << lb); \
      vf2 a_, b_, t0_, t1_, r0_, r1_; \
      a_.x = st[2*w0]; a_.y = st[2*w0+1]; \
      b_.x = st[2*w1]; b_.y = st[2*w1+1]; \
      asm("v_pk_mul_f32 %0, %1, %2"     : "=v"(t0_) : "v"(a_), "v"(cc_)); \
      asm("v_pk_fma_f32 %0, %1, %2, %3" : "=v"(r0_) : "v"(b_), "v"(ns_), "v"(t0_)); \
      asm("v_pk_mul_f32 %0, %1, %2"     : "=v"(t1_) : "v"(a_), "v"(ss_)); \
      asm("v_pk_fma_f32 %0, %1, %2, %3" : "=v"(r1_) : "v"(b_), "v"(cc_), "v"(t1_)); \
      st[2*w0] = r0_.x; st[2*w0+1] = r0_.y; \
      st[2*w1] = r1_.x; st[2*w1+1] = r1_.y; \
    } \
  } \
}while(0)

// swap lane-domain <-> reg-domain through LDS (conflict-free b64 writes / b128 reads);
// single wave -> in-order LDS pipe, no barrier needed
#define TRANSPOSE() do{ \
  _Pragma("unroll") \
  for (int w = 0; w < 64; w++){ \
    vf2 t_; t_.x = st[2*w]; t_.y = st[2*w+1]; \
    xbuf[w * ROWS + u] = t_; \
  } \
  FENCE(); \
  _Pragma("unroll") \
  for (int j = 0; j < 32; j++){ \
    float4 f_ = ((const float4*)&xbuf[u * ROWS])[j]; \
    st[4*j] = f_.x; st[4*j+1] = f_.y; st[4*j+2] = f_.z; st[4*j+3] = f_.w; \
  } \
  FENCE(); \
}while(0)

// merged diagonal d (runtime): reg part from tabs, lane part from ltab, cross CZ inline
#define DIAG(d, par) do{ \
  vf2 lp_ = ltab[(d)-1][u]; \
  vf2 lpn_ = -lp_; \
  const int u0_ = u & 1, u1_ = (u >> 1) & 1, u4_ = (u >> 4) & 1, u5_ = (u >> 5) & 1; \
  _Pragma("unroll") \
  for (int w = 0; w < 64; w++){ \
    vf2 dph_ = tabs[(d)-1][w]; \
    int sx_; \
    if (par) sx_ = ((w & 1) * u5_) ^ (((w >> 5) & 1) * u0_); \
    else     sx_ = (((w >> 5) & 1) * u1_) ^ (((w >> 4) & 1) * u0_) \
                 ^ (((w >> 1) & 1) * u5_) ^ ((w & 1) * u4_); \
    vf2 a_; a_.x = st[2*w]; a_.y = st[2*w+1]; \
    vf2 t_ = cmulv(a_, dph_); \
    vf2 r_ = cmulv(t_, sx_ ? lpn_ : lp_); \
    st[2*w] = r_.x; st[2*w+1] = r_.y; \
  } \
}while(0)

__global__ __attribute__((amdgpu_flat_work_group_size(64,64)))
__attribute__((amdgpu_waves_per_eu(1)))
void qiddm_wave(const float* __restrict__ gx,
                const float* __restrict__ gcw,
                const float* __restrict__ gcb,
                const float* __restrict__ gw1,
                const float* __restrict__ glw,
                const float* __restrict__ glb,
                float* __restrict__ gout)
{
  // One wave per sample; 4096-amp state in ONE ext_vector (mem2reg-guaranteed registers).
  // L0 layout: lane u = idx bits 11..6 (wires 0..5), reg w = idx bits 5..0 (wires 6..11)
  // L1 layout: lane u = idx bits 5..0,  reg w = idx bits 11..6
  // Occupancy note (rounds 0-3): residency is pinned at ~1 wave/SIMD regardless of LDS
  // (39.9/18.9/37.4 KB) and WG shape (1- or 2-wave). This round attacks VALU instruction
  // count instead (packed math + product-state init); round-0 structure restored.
  __shared__ vf2 xbuf[64 * ROWS];   // 33792 B transpose buffer (aliases conv image)
  __shared__ vf2 tabs[5][64];       // reg-domain diagonal tables
  __shared__ vf2 ltab[5][64];       // lane-domain diagonal factors
  __shared__ vf2 scsl[72];          // (cos, sin) of theta/2 per (sublayer, wire)

  const int u = threadIdx.x;        // lane 0..63
  const int bid = blockIdx.x;

  float xr[12];                     // circuit inputs / expvals (constant-indexed only)

  // ---------- conv 3x3 s2 p1 + bias + GAP ----------
  {
    float* img = (float*)xbuf;
#pragma unroll
    for (int i = 0; i < 4; i++){
      float4 q4 = ((const float4*)gx)[(size_t)bid * 256 + i * 64 + u];
      ((float4*)img)[i * 64 + u] = q4;
    }
    float p[4][9];
#pragma unroll
    for (int i = 0; i < 4; i++){
      int pos = u + 64 * i, oi = pos >> 4, oj = pos & 15;
#pragma unroll
      for (int ki = 0; ki < 3; ki++)
#pragma unroll
        for (int kj = 0; kj < 3; kj++){
          int ri = 2*oi - 1 + ki, cj = 2*oj - 1 + kj;
          p[i][ki*3+kj] = (ri >= 0 && ri < 32 && cj >= 0 && cj < 32) ? img[ri*32+cj] : 0.0f;
        }
    }
#pragma unroll
    for (int q = 0; q < 12; q++){
      float a = 0.0f;
#pragma unroll
      for (int e = 0; e < 9; e++){
        float wv = gcw[q*9+e];                  // uniform -> scalarized
#pragma unroll
        for (int i = 0; i < 4; i++) a += p[i][e] * wv;
      }
#pragma unroll
      for (int off = 32; off; off >>= 1) a += __shfl_xor(a, off);
      xr[q] = gcb[q] + a * (1.0f/256.0f);
    }
  }

#pragma unroll 1
  for (int n = 0; n < 2; n++){
    const float* W = gw1 + n * 216;

    // ---- RY cos/sin table (72 gates) ----
#pragma unroll
    for (int rep = 0; rep < 2; rep++){
      int e = u + rep * 64;
      if (e < 72){
        float sv, cv; __sincosf(0.5f * W[e*3+1], &sv, &cv);
        vf2 cs; cs.x = cv; cs.y = sv; scsl[e] = cs;
      }
    }

    // ---- diagonal tables: reg-domain (tabs) and lane-domain (ltab), d unrolled ----
#pragma unroll
    for (int d = 1; d <= 5; d++){
      const int par = d & 1;                    // 1 -> applied in L1 (r=1), 0 -> L0 (r=2)
      const int r = par ? 1 : 2;
      {
        float ph = 0.0f;
#pragma unroll
        for (int lb = 0; lb < 6; lb++){
          int wire = par ? (5 - lb) : (11 - lb);          // reg-domain wires
          ph += ALPHA(d, wire) * ((float)((u >> lb) & 1) - 0.5f);
        }
        int idx_r = par ? (u << 6) : u;
        int y = ((idx_r << r) | (idx_r >> (12 - r))) & 0xFFF;
        int s = __popc(idx_r & y) & 1;                    // within-reg CZ parity
        float sv, cv; __sincosf(ph, &sv, &cv);
        vf2 e_; e_.x = cv; e_.y = sv; if (s) e_ = -e_;
        tabs[d-1][u] = e_;
      }
      {
        float ph = 0.0f;
#pragma unroll
        for (int lb = 0; lb < 6; lb++){
          int wire = par ? (11 - lb) : (5 - lb);          // lane-domain wires
          ph += ALPHA(d, wire) * ((float)((u >> lb) & 1) - 0.5f);
        }
        int idx_l = par ? u : (u << 6);
        int y = ((idx_l << r) | (idx_l >> (12 - r))) & 0xFFF;
        int s = __popc(idx_l & y) & 1;                    // within-lane CZ parity
        float sv, cv; __sincosf(ph, &sv, &cv);
        vf2 e_; e_.x = cv; e_.y = sv; if (s) e_ = -e_;
        ltab[d-1][u] = e_;
      }
    }
    FENCE();                                    // table writes before circuit reads

    // ---- direct product-state init in L1 (replaces k=0: GATES6, k=1: TRANSPOSE+GATES6)
    // After sublayer-0's 12 RY gates on |0...0> the state is the pure product
    // state ⊗_j (c_j|0> + s_j|1>).  In L1: amp(u,w) = L(u)·Q(w), purely real.
    // L(u) = Π_lb (u_lb ? s_{11-lb} : c_{11-lb});  Q(w) = Π_rb (w_rb ? s_{5-rb} : c_{5-rb})
    v128f st;
    float fl = 1.0f;
#pragma unroll
    for (int lb = 0; lb < 6; lb++){
      vf2 cs = scsl[11 - lb];
      fl *= ((u >> lb) & 1) ? cs.y : cs.x;      // runtime select, constant index
    }
    float qc[6], qs[6];
#pragma unroll
    for (int rb = 0; rb < 6; rb++){ vf2 cs = scsl[5 - rb]; qc[rb] = cs.x; qs[rb] = cs.y; }
#pragma unroll
    for (int w = 0; w < 64; w++){               // w compile-time -> selects fold, CSE shares
      float Qw =  ((w & 1)  ? qs[0] : qc[0]);
      Qw      *=  ((w & 2)  ? qs[1] : qc[1]);
      Qw      *=  ((w & 4)  ? qs[2] : qc[2]);
      Qw      *=  ((w & 8)  ? qs[3] : qc[3]);
      Qw      *=  ((w & 16) ? qs[4] : qc[4]);
      Qw      *=  ((w & 32) ? qs[5] : qc[5]);
      st[2*w] = fl * Qw; st[2*w+1] = 0.0f;
    }

    // ---- circuit: 10 remaining half-sublayer steps (k=2..11), measure ----
#pragma unroll 1
    for (int k = 2; k < 12; k++){
      const int sl  = k >> 1;
      const int par = ((k + 1) >> 1) & 1;
      if (k & 1) TRANSPOSE();                   // flip lane/reg domains
      else       DIAG(sl, par);                 // D_sl before the sublayer's 2nd half
      GATES6(sl, par);
    }

    // ---- measurement in L0 (final omega-diagonal is a pure phase: dropped) ----
    {
      float P = 0.f, mm[6] = {0.f,0.f,0.f,0.f,0.f,0.f};  // wires 6..11 (reg bits 5..0)
#pragma unroll
      for (int w = 0; w < 64; w++){
        float re = st[2*w], im = st[2*w+1];
        float pr = re*re + im*im;
        P += pr;
#pragma unroll
        for (int i = 0; i < 6; i++)
          mm[i] += ((w >> (5 - i)) & 1) ? -pr : pr;
      }
#pragma unroll
      for (int q = 0; q < 12; q++){
        float val = (q < 6) ? (((u >> (5 - q)) & 1) ? -P : P)   // wires 0..5 (lane bits)
                            : mm[q - 6];
#pragma unroll
        for (int off = 32; off; off >>= 1) val += __shfl_xor(val, off);
        xr[q] = val;                            // uniform across lanes after butterfly
      }
    }
  }

  // ---------- final linear ----------
  {
#pragma unroll
    for (int i = 0; i < 16; i++){
      int o = i * 64 + u;
      const float4* wr = (const float4*)(glw + o * 12);   // 48B rows, 16B aligned
      float4 w0 = wr[0], w1 = wr[1], w2 = wr[2];
      float a = glb[o];
      a += xr[0]*w0.x + xr[1]*w0.y + xr[2]*w0.z + xr[3]*w0.w;
      a += xr[4]*w1.x + xr[5]*w1.y + xr[6]*w1.z + xr[7]*w1.w;
      a += xr[8]*w2.x + xr[9]*w2.y + xr[10]*w2.z + xr[11]*w2.w;
      gout[(size_t)bid * 1024 + o] = a;
    }
  }
}

extern "C" void kernel_launch(void* const* d_in, const int* in_sizes, int n_in,
                              void* d_out, int out_size, void* d_ws, size_t ws_size,
                              hipStream_t stream)
{
  (void)n_in; (void)d_ws; (void)ws_size; (void)out_size;
  const float* x  = (const float*)d_in[0];
  const float* cw = (const float*)d_in[1];
  const float* cb = (const float*)d_in[2];
  const float* w1 = (const float*)d_in[3];
  const float* lw = (const float*)d_in[4];
  const float* lb = (const float*)d_in[5];
  float* out = (float*)d_out;
  const int nb = in_sizes[0] / 1024;   // 2048 samples, one wave each
  hipLaunchKernelGGL(qiddm_wave, dim3(nb), dim3(64), 0, stream,
                     x, cw, cb, w1, lw, lb, out);
}

// Round 5
// 182.913 us; speedup vs baseline: 1.3067x; 1.1594x over previous
//
#include <hip/hip_runtime.h>

typedef float vf2  __attribute__((ext_vector_type(2)));
typedef float v128f __attribute__((ext_vector_type(128)));

__device__ __forceinline__ vf2 cmulv(vf2 a, vf2 b){
  vf2 br; br.x = -b.y; br.y = b.x;
  return a.x*b + a.y*br;
}

#define ROWS 66   // transpose-buffer row stride in float2 (64 + 2 pad -> bank stagger)
#define FENCE() asm volatile("" ::: "memory")

// merged-diagonal angle for wire j of diagonal d (wave-uniform); d, j compile-time
#define ALPHA(d, j) (((d) & 1) \
  ? (W[((((d)>>1)*2+1)*12+(j))*3+0] + W[((((d)>>1)*2+0)*12+(j))*3+2]) \
  : (W[((((d)>>1)*2+0)*12+(j))*3+0] + xr[(j)] + W[(((((d)>>1)-1)*2+1)*12+(j))*3+2]))

// 6 RY gates on the reg-domain bits -- TAN-FORM with deferred cosine:
//   true r0 = c*a - s*b = c*(a - t*b);  true r1 = s*a + c*b = c*(b + t*a)
// We compute the parenthesized part only (4 FMAs/butterfly instead of 8 ops) and
// defer the uniform factor c.  The product of all deferred c's is applied once at
// measurement as C^2 on the probabilities (exact, uniform scaling).
#define GATES6(sl, par) do{ \
  _Pragma("unroll") \
  for (int lb = 0; lb < 6; lb++){ \
    const int wire_ = (par) ? (5 - lb) : (11 - lb); \
    const float t_ = scsl[(sl)*12 + wire_].y; \
    _Pragma("unroll") \
    for (int w0 = 0; w0 < 64; w0++){ \
      if (w0 & (1 << lb)) continue; \
      const int w1 = w0 | (1 << lb); \
      const float ax_ = st[2*w0], ay_ = st[2*w0+1]; \
      const float bx_ = st[2*w1], by_ = st[2*w1+1]; \
      st[2*w0]   = __builtin_fmaf(-t_, bx_, ax_); \
      st[2*w0+1] = __builtin_fmaf(-t_, by_, ay_); \
      st[2*w1]   = __builtin_fmaf( t_, ax_, bx_); \
      st[2*w1+1] = __builtin_fmaf( t_, ay_, by_); \
    } \
  } \
}while(0)

// swap lane-domain <-> reg-domain through LDS (conflict-free b64 writes / b128 reads);
// single wave -> in-order LDS pipe, no barrier needed
#define TRANSPOSE() do{ \
  _Pragma("unroll") \
  for (int w = 0; w < 64; w++){ \
    vf2 t_; t_.x = st[2*w]; t_.y = st[2*w+1]; \
    xbuf[w * ROWS + u] = t_; \
  } \
  FENCE(); \
  _Pragma("unroll") \
  for (int j = 0; j < 32; j++){ \
    float4 f_ = ((const float4*)&xbuf[u * ROWS])[j]; \
    st[4*j] = f_.x; st[4*j+1] = f_.y; st[4*j+2] = f_.z; st[4*j+3] = f_.w; \
  } \
  FENCE(); \
}while(0)

// merged diagonal d (runtime): reg part from tabs, lane part from ltab; cross-domain
// CZ parity via per-lane bitmask + popc (parity of selected w-bits == xor of products)
#define DIAG(d, par) do{ \
  vf2 lp_ = ltab[(d)-1][u]; \
  vf2 lpn_ = -lp_; \
  const unsigned m_ = (par) ? ( ((u >> 5) & 1u) | ((u & 1u) << 5) ) \
                            : ( (((u >> 1) & 1u) << 5) | ((u & 1u) << 4) \
                              | (((u >> 5) & 1u) << 1) | ((u >> 4) & 1u) ); \
  _Pragma("unroll") \
  for (int w = 0; w < 64; w++){ \
    vf2 dph_ = tabs[(d)-1][w]; \
    const int sx_ = __popc((unsigned)w & m_) & 1; \
    vf2 a_; a_.x = st[2*w]; a_.y = st[2*w+1]; \
    vf2 t_ = cmulv(a_, dph_); \
    vf2 r_ = cmulv(t_, sx_ ? lpn_ : lp_); \
    st[2*w] = r_.x; st[2*w+1] = r_.y; \
  } \
}while(0)

__global__ __attribute__((amdgpu_flat_work_group_size(64,64)))
__attribute__((amdgpu_waves_per_eu(1)))
void qiddm_wave(const float* __restrict__ gx,
                const float* __restrict__ gcw,
                const float* __restrict__ gcb,
                const float* __restrict__ gw1,
                const float* __restrict__ glw,
                const float* __restrict__ glb,
                float* __restrict__ gout)
{
  // One wave per sample; 4096-amp state in ONE ext_vector (mem2reg-guaranteed registers).
  // L0 layout: lane u = idx bits 11..6 (wires 0..5), reg w = idx bits 5..0 (wires 6..11)
  // L1 layout: lane u = idx bits 5..0,  reg w = idx bits 11..6
  // Rounds 0-4 established: residency pinned ~1 wave/SIMD regardless of LDS/WG shape;
  // wall time tracks SCALAR VALU op count (packed-asm encoding didn't help -- marshalling).
  // This round halves the dominant butterfly cost mathematically (tan-form, deferred c).
  __shared__ vf2 xbuf[64 * ROWS];   // 33792 B transpose buffer (aliases conv image)
  __shared__ vf2 tabs[5][64];       // reg-domain diagonal tables
  __shared__ vf2 ltab[5][64];       // lane-domain diagonal factors
  __shared__ vf2 scsl[72];          // (cos, tan) of theta/2 per (sublayer, wire)

  const int u = threadIdx.x;        // lane 0..63
  const int bid = blockIdx.x;

  float xr[12];                     // circuit inputs / expvals (constant-indexed only)

  // ---------- conv 3x3 s2 p1 + bias + GAP ----------
  {
    float* img = (float*)xbuf;
#pragma unroll
    for (int i = 0; i < 4; i++){
      float4 q4 = ((const float4*)gx)[(size_t)bid * 256 + i * 64 + u];
      ((float4*)img)[i * 64 + u] = q4;
    }
    float p[4][9];
#pragma unroll
    for (int i = 0; i < 4; i++){
      int pos = u + 64 * i, oi = pos >> 4, oj = pos & 15;
#pragma unroll
      for (int ki = 0; ki < 3; ki++)
#pragma unroll
        for (int kj = 0; kj < 3; kj++){
          int ri = 2*oi - 1 + ki, cj = 2*oj - 1 + kj;
          p[i][ki*3+kj] = (ri >= 0 && ri < 32 && cj >= 0 && cj < 32) ? img[ri*32+cj] : 0.0f;
        }
    }
#pragma unroll
    for (int q = 0; q < 12; q++){
      float a = 0.0f;
#pragma unroll
      for (int e = 0; e < 9; e++){
        float wv = gcw[q*9+e];                  // uniform -> scalarized
#pragma unroll
        for (int i = 0; i < 4; i++) a += p[i][e] * wv;
      }
#pragma unroll
      for (int off = 32; off; off >>= 1) a += __shfl_xor(a, off);
      xr[q] = gcb[q] + a * (1.0f/256.0f);
    }
  }

#pragma unroll 1
  for (int n = 0; n < 2; n++){
    const float* W = gw1 + n * 216;

    // ---- RY (cos, tan) table (72 gates) + deferred-cosine product C = prod c[12..71]
    // (gates 0..11 = sublayer 0 are applied exactly by the product-state init below,
    //  so only the 60 tan-form gates contribute to the deferred scale)
    float myc = 1.0f;
#pragma unroll
    for (int rep = 0; rep < 2; rep++){
      int e = u + rep * 64;
      if (e < 72){
        float sv, cv; __sincosf(0.5f * W[e*3+1], &sv, &cv);
        vf2 ct; ct.x = cv; ct.y = __fdividef(sv, cv); scsl[e] = ct;
        if (e >= 12) myc *= cv;
      }
    }
#pragma unroll
    for (int off = 32; off; off >>= 1) myc *= __shfl_xor(myc, off);
    const float C2 = myc * myc;                 // wave-uniform probability scale

    // ---- diagonal tables: reg-domain (tabs) and lane-domain (ltab), d unrolled ----
#pragma unroll
    for (int d = 1; d <= 5; d++){
      const int par = d & 1;                    // 1 -> applied in L1 (r=1), 0 -> L0 (r=2)
      const int r = par ? 1 : 2;
      {
        float ph = 0.0f;
#pragma unroll
        for (int lb = 0; lb < 6; lb++){
          int wire = par ? (5 - lb) : (11 - lb);          // reg-domain wires
          ph += ALPHA(d, wire) * ((float)((u >> lb) & 1) - 0.5f);
        }
        int idx_r = par ? (u << 6) : u;
        int y = ((idx_r << r) | (idx_r >> (12 - r))) & 0xFFF;
        int s = __popc(idx_r & y) & 1;                    // within-reg CZ parity
        float sv, cv; __sincosf(ph, &sv, &cv);
        vf2 e_; e_.x = cv; e_.y = sv; if (s) e_ = -e_;
        tabs[d-1][u] = e_;
      }
      {
        float ph = 0.0f;
#pragma unroll
        for (int lb = 0; lb < 6; lb++){
          int wire = par ? (11 - lb) : (5 - lb);          // lane-domain wires
          ph += ALPHA(d, wire) * ((float)((u >> lb) & 1) - 0.5f);
        }
        int idx_l = par ? u : (u << 6);
        int y = ((idx_l << r) | (idx_l >> (12 - r))) & 0xFFF;
        int s = __popc(idx_l & y) & 1;                    // within-lane CZ parity
        float sv, cv; __sincosf(ph, &sv, &cv);
        vf2 e_; e_.x = cv; e_.y = sv; if (s) e_ = -e_;
        ltab[d-1][u] = e_;
      }
    }
    FENCE();                                    // table writes before circuit reads

    // ---- direct product-state init in L1 (replaces k=0,1: sublayer 0 entirely)
    // After sublayer-0's 12 RY gates on |0...0> the state is ⊗_j (c_j|0> + s_j|1>),
    // s_j = c_j * t_j.  In L1: amp(u,w) = L(u)·Q(w), purely real.
    v128f st;
    float fl = 1.0f;
#pragma unroll
    for (int lb = 0; lb < 6; lb++){
      vf2 ct = scsl[11 - lb];
      fl *= ((u >> lb) & 1) ? (ct.x * ct.y) : ct.x;   // runtime select, constant index
    }
    float qc[6], qs[6];
#pragma unroll
    for (int rb = 0; rb < 6; rb++){
      vf2 ct = scsl[5 - rb]; qc[rb] = ct.x; qs[rb] = ct.x * ct.y;
    }
#pragma unroll
    for (int w = 0; w < 64; w++){               // w compile-time -> selects fold, CSE shares
      float Qw =  ((w & 1)  ? qs[0] : qc[0]);
      Qw      *=  ((w & 2)  ? qs[1] : qc[1]);
      Qw      *=  ((w & 4)  ? qs[2] : qc[2]);
      Qw      *=  ((w & 8)  ? qs[3] : qc[3]);
      Qw      *=  ((w & 16) ? qs[4] : qc[4]);
      Qw      *=  ((w & 32) ? qs[5] : qc[5]);
      st[2*w] = fl * Qw; st[2*w+1] = 0.0f;
    }

    // ---- circuit: 10 remaining half-sublayer steps (k=2..11), measure ----
#pragma unroll 1
    for (int k = 2; k < 12; k++){
      const int sl  = k >> 1;
      const int par = ((k + 1) >> 1) & 1;
      if (k & 1) TRANSPOSE();                   // flip lane/reg domains
      else       DIAG(sl, par);                 // D_sl before the sublayer's 2nd half
      GATES6(sl, par);
    }

    // ---- measurement in L0; computed state = true/C, so p_true = p~ * C2 ----
    {
      float P = 0.f, mm[6] = {0.f,0.f,0.f,0.f,0.f,0.f};  // wires 6..11 (reg bits 5..0)
#pragma unroll
      for (int w = 0; w < 64; w++){
        float re = st[2*w], im = st[2*w+1];
        float pr = re*re + im*im;
        P += pr;
#pragma unroll
        for (int i = 0; i < 6; i++)
          mm[i] += ((w >> (5 - i)) & 1) ? -pr : pr;
      }
#pragma unroll
      for (int q = 0; q < 12; q++){
        float val = (q < 6) ? (((u >> (5 - q)) & 1) ? -P : P)   // wires 0..5 (lane bits)
                            : mm[q - 6];
#pragma unroll
        for (int off = 32; off; off >>= 1) val += __shfl_xor(val, off);
        xr[q] = val * C2;                       // undo deferred cosines (uniform)
      }
    }
  }

  // ---------- final linear ----------
  {
#pragma unroll
    for (int i = 0; i < 16; i++){
      int o = i * 64 + u;
      const float4* wr = (const float4*)(glw + o * 12);   // 48B rows, 16B aligned
      float4 w0 = wr[0], w1 = wr[1], w2 = wr[2];
      float a = glb[o];
      a += xr[0]*w0.x + xr[1]*w0.y + xr[2]*w0.z + xr[3]*w0.w;
      a += xr[4]*w1.x + xr[5]*w1.y + xr[6]*w1.z + xr[7]*w1.w;
      a += xr[8]*w2.x + xr[9]*w2.y + xr[10]*w2.z + xr[11]*w2.w;
      gout[(size_t)bid * 1024 + o] = a;
    }
  }
}

extern "C" void kernel_launch(void* const* d_in, const int* in_sizes, int n_in,
                              void* d_out, int out_size, void* d_ws, size_t ws_size,
                              hipStream_t stream)
{
  (void)n_in; (void)d_ws; (void)ws_size; (void)out_size;
  const float* x  = (const float*)d_in[0];
  const float* cw = (const float*)d_in[1];
  const float* cb = (const float*)d_in[2];
  const float* w1 = (const float*)d_in[3];
  const float* lw = (const float*)d_in[4];
  const float* lb = (const float*)d_in[5];
  float* out = (float*)d_out;
  const int nb = in_sizes[0] / 1024;   // 2048 samples, one wave each
  hipLaunchKernelGGL(qiddm_wave, dim3(nb), dim3(64), 0, stream,
                     x, cw, cb, w1, lw, lb, out);
}